// Round 14
// baseline (215.751 us; speedup 1.0000x reference)
//
#include <hip/hip_runtime.h>
#include <hip/hip_bf16.h>

#define M_DIM 4096
#define N_DIM 4096
#define K_DIM 4096

typedef __attribute__((ext_vector_type(8))) __bf16 bf16x8;
typedef __attribute__((ext_vector_type(8))) short short8;
typedef __attribute__((ext_vector_type(8))) unsigned short ushort8;
typedef __attribute__((ext_vector_type(4))) float f32x4;

// async global->LDS, 16B/lane (m104: dest = wave-uniform base + lane*16)
__device__ __forceinline__ void gload_lds16(const void* g, void* l) {
    __builtin_amdgcn_global_load_lds(
        (const __attribute__((address_space(1))) void*)g,
        (__attribute__((address_space(3))) void*)l,
        16, 0, 0);
}

__device__ __forceinline__ bf16x8 ld8(const unsigned short* p) {
    short8 r = *reinterpret_cast<const short8*>(p);
    return __builtin_bit_cast(bf16x8, r);
}

// ---------------------------------------------------------------------------
// fused fp32->bf16 conversion: x (pruned) and w (unpruned) in ONE launch
// ---------------------------------------------------------------------------
__global__ void prune_cvt2(const float* __restrict__ x,
                           const float* __restrict__ w,
                           unsigned short* __restrict__ xb,
                           unsigned short* __restrict__ wb,
                           const float* __restrict__ thrp, int n8) {
    const float thr = thrp[0];
    const int stride = gridDim.x * blockDim.x;
    const int total = 2 * n8;
    for (int idx = blockIdx.x * blockDim.x + threadIdx.x; idx < total; idx += stride) {
        const bool isx = idx < n8;
        const int j = isx ? idx : idx - n8;
        const float* src = isx ? x : w;
        unsigned short* dst = isx ? xb : wb;
        const float te = isx ? thr : -1.0f;   // |v| > -1 always true -> keep all
        const float4* p = reinterpret_cast<const float4*>(src) + 2 * (size_t)j;
        float4 v0 = p[0];
        float4 v1 = p[1];
        float v[8] = {v0.x, v0.y, v0.z, v0.w, v1.x, v1.y, v1.z, v1.w};
        ushort8 o;
#pragma unroll
        for (int e = 0; e < 8; ++e) {
            float f = v[e];
            f = (fabsf(f) > te) ? f : 0.0f;   // prune in fp32 (exact predicate)
            __hip_bfloat16 hh = __float2bfloat16(f);
            o[e] = *reinterpret_cast<unsigned short*>(&hh);
        }
        *reinterpret_cast<ushort8*>(dst + 8 * (size_t)j) = o;
    }
}

// ---------------------------------------------------------------------------
// C = A * B^T, 256x256 tile, BK=64, 8 waves, 16x16x32 MFMA.
// A: LDS double-buffered (R13 champion path, 4x gload_lds @ph0, single
//    lgkmcnt(0)+vmcnt(0)+barrier @end-ph2, ph3 pre-reads next tile).
// B: NEVER staged to LDS — fragments load global->register (L2-resident by
//    XCD swizzle: each XCD's 32 blocks share 2 bn panels = 4MB = L2 size).
//    Cuts LDS-engine demand ~27% (the measured bound at R13).
//
// kk-major phases: {m0-3/kk0, m4-7/kk0, m0-3/kk1, m4-7/kk1}; B-reg schedule:
//   Bkk1(t) loaded @ph0(t) (used ph2, 2-phase slack)
//   Bkk0(t+1) loaded @ph3(t) (used next ph0, 1-phase slack)
// Per-phase: 4 ds_read_b128 (A-frags, 1 phase ahead) + 0/4 global B loads.
// ---------------------------------------------------------------------------
__global__ __launch_bounds__(512, 2) void gemm_bgl(
        const unsigned short* __restrict__ A,
        const unsigned short* __restrict__ B,
        float* __restrict__ C) {
    __shared__ __align__(16) unsigned short lds[32768];  // 64 KB: A[2][256][64]

    const int tid  = threadIdx.x;
    const int lane = tid & 63;
    const int wid  = tid >> 6;
    const int wr   = wid >> 2;   // 0..1 : 128-row strip
    const int wc   = wid & 3;    // 0..3 : 64-col strip

    // XCD swizzle: each XCD (bid&7) owns 2 bn panels x 16 bm -> B L2-resident
    const int xcd = blockIdx.x & 7;
    const int idx = blockIdx.x >> 3;          // 0..31
    const int bn  = (xcd * 2 + (idx >> 4)) * 256;
    const int bm  = (idx & 15) * 256;

    // A staging: A-half ah staged by threads [ah*256,+256); load j = rows [32j,+32)
    const int g  = tid & 255;
    const int ah = tid >> 8;
    const int arow = bm + ah * 128 + (g >> 3);
    const int acol = 8 * ((g & 7) ^ ((g >> 3) & 7));      // pre-swizzled source col
    const unsigned short* Asrc = A + (size_t)arow * K_DIM + acol;
    const int AdstE = ah * 8192 + g * 8;

#define SA(dstb, j, kg) gload_lds16(Asrc + (size_t)(32*(j))*K_DIM + (kg), (dstb) + AdstE + 2048*(j))

    // fragment read offsets (row&7 == fr&7 -> swizzle slot is thread-constant)
    const int fr  = lane & 15;
    const int kq4 = lane >> 4;
    const int rowOffA = (wr * 128 + fr) * 64;
    const int sk0 = 8 * ((kq4    ) ^ (fr & 7));
    const int sk1 = 8 * ((kq4 + 4) ^ (fr & 7));

    // B fragment global base pointers (per lane), n = 0..3
    const unsigned short* bp0 = B + (size_t)(bn + wc * 64 +  0 + fr) * K_DIM + kq4 * 8;
    const unsigned short* bp1 = bp0 + (size_t)16 * K_DIM;
    const unsigned short* bp2 = bp0 + (size_t)32 * K_DIM;
    const unsigned short* bp3 = bp0 + (size_t)48 * K_DIM;

    f32x4 acc[8][4] = {};
    bf16x8 aA0, aA1, aA2, aA3, aB0, aB1, aB2, aB3;   // A frag sets (alternate)
    bf16x8 e0[4], e1[4], o0[4], o1[4];               // B frags: even/odd x kk0/kk1

#define PH_MFMA(q, S0, S1, S2, S3, T)                                                              \
    __builtin_amdgcn_s_setprio(1);                                                                 \
    {                                                                                              \
        const bf16x8 Av_[4] = {S0, S1, S2, S3};                                                    \
        _Pragma("unroll")                                                                          \
        for (int i_ = 0; i_ < 4; ++i_)                                                             \
            _Pragma("unroll")                                                                      \
            for (int n_ = 0; n_ < 4; ++n_)                                                         \
                acc[4*(q)+i_][n_] = __builtin_amdgcn_mfma_f32_16x16x32_bf16(                       \
                    Av_[i_], T[n_], acc[4*(q)+i_][n_], 0, 0, 0);                                   \
    }                                                                                              \
    __builtin_amdgcn_s_setprio(0);

    // One K-tile. BC0/BC1 = current tile's B frags (kk0 loaded last ph3 /
    // kk1 loaded here at ph0); BN0 = next tile's kk0 (loaded ph3).
#define TILE_BODY(Ab, AbN, BC0, BC1, BN0, kc, kna, knb)                                            \
    {                                                                                              \
        /* ph0: MFMA m0-3/kk0 [aA,BC0]; read A m4-7/kk0; load BC1; SA x4 */                        \
        BC1[0] = ld8(bp0 + (kc) + 32);                                                             \
        BC1[1] = ld8(bp1 + (kc) + 32);                                                             \
        BC1[2] = ld8(bp2 + (kc) + 32);                                                             \
        BC1[3] = ld8(bp3 + (kc) + 32);                                                             \
        aB0 = ld8((Ab) + rowOffA + 4 * 1024 + sk0);                                                \
        aB1 = ld8((Ab) + rowOffA + 5 * 1024 + sk0);                                                \
        aB2 = ld8((Ab) + rowOffA + 6 * 1024 + sk0);                                                \
        aB3 = ld8((Ab) + rowOffA + 7 * 1024 + sk0);                                                \
        SA((AbN), 0, (kna)); SA((AbN), 1, (kna)); SA((AbN), 2, (kna)); SA((AbN), 3, (kna));        \
        PH_MFMA(0, aA0, aA1, aA2, aA3, BC0);                                                       \
        /* ph1: MFMA m4-7/kk0 [aB,BC0]; read A m0-3/kk1 */                                         \
        aA0 = ld8((Ab) + rowOffA + 0 * 1024 + sk1);                                                \
        aA1 = ld8((Ab) + rowOffA + 1 * 1024 + sk1);                                                \
        aA2 = ld8((Ab) + rowOffA + 2 * 1024 + sk1);                                                \
        aA3 = ld8((Ab) + rowOffA + 3 * 1024 + sk1);                                                \
        PH_MFMA(1, aB0, aB1, aB2, aB3, BC0);                                                       \
        /* ph2: MFMA m0-3/kk1 [aA,BC1]; read A m4-7/kk1; SINGLE sync */                            \
        aB0 = ld8((Ab) + rowOffA + 4 * 1024 + sk1);                                                \
        aB1 = ld8((Ab) + rowOffA + 5 * 1024 + sk1);                                                \
        aB2 = ld8((Ab) + rowOffA + 6 * 1024 + sk1);                                                \
        aB3 = ld8((Ab) + rowOffA + 7 * 1024 + sk1);                                                \
        PH_MFMA(0, aA0, aA1, aA2, aA3, BC1);                                                       \
        asm volatile("s_waitcnt lgkmcnt(0) vmcnt(0)" ::: "memory");                                \
        asm volatile("s_barrier" ::: "memory");                                                    \
        /* ph3: MFMA m4-7/kk1 [aB,BC1]; load BN0 (kk0 of t+1); pre-read A(t+1) m0-3/kk0 */         \
        BN0[0] = ld8(bp0 + (knb));                                                                 \
        BN0[1] = ld8(bp1 + (knb));                                                                 \
        BN0[2] = ld8(bp2 + (knb));                                                                 \
        BN0[3] = ld8(bp3 + (knb));                                                                 \
        aA0 = ld8((AbN) + rowOffA + 0 * 1024 + sk0);                                               \
        aA1 = ld8((AbN) + rowOffA + 1 * 1024 + sk0);                                               \
        aA2 = ld8((AbN) + rowOffA + 2 * 1024 + sk0);                                               \
        aA3 = ld8((AbN) + rowOffA + 3 * 1024 + sk0);                                               \
        PH_MFMA(1, aB0, aB1, aB2, aB3, BC1);                                                       \
    }

    // compile-time buffer bases
    unsigned short* A0 = lds;
    unsigned short* A1 = lds + 16384;

    // ---- prologue: stage A(0)->buf0; load B(0) kk0 -> e0; land; pre-read aA
    SA(A0, 0, 0); SA(A0, 1, 0); SA(A0, 2, 0); SA(A0, 3, 0);
    e0[0] = ld8(bp0); e0[1] = ld8(bp1); e0[2] = ld8(bp2); e0[3] = ld8(bp3);
    asm volatile("s_waitcnt vmcnt(0)" ::: "memory");
    asm volatile("s_barrier" ::: "memory");

    aA0 = ld8(A0 + rowOffA + 0 * 1024 + sk0);
    aA1 = ld8(A0 + rowOffA + 1 * 1024 + sk0);
    aA2 = ld8(A0 + rowOffA + 2 * 1024 + sk0);
    aA3 = ld8(A0 + rowOffA + 3 * 1024 + sk0);

    for (int t = 0; t < 64; t += 2) {
        const int kc0 = t * 64;
        const int kc1 = (t + 1) * 64;
        const int kna0 = (t + 1) * 64;                     // t+1 <= 63, never clamps
        const int kna1 = (t + 2 < 64 ? t + 2 : 63) * 64;   // clamp: tail stage is dead
        const int knb0 = kc1;                              // B kk0 of tile t+1
        const int knb1 = kna1;                             // B kk0 of tile t+2 (clamped)
        // even tile t: A from buf0, B frags e*; stage A(t+1)->buf1; next B -> o0
        TILE_BODY(A0, A1, e0, e1, o0, kc0, kna0, knb0);
        // odd tile t+1: A from buf1, B frags o*; stage A(t+2)->buf0; next B -> e0
        TILE_BODY(A1, A0, o0, o1, e0, kc1, kna1, knb1);
    }

    asm volatile("s_waitcnt vmcnt(0)" ::: "memory");  // drain dead tail stages

    // C/D layout (m89): col = lane&15, row = (lane>>4)*4 + j
    const int crow = bm + wr * 128 + kq4 * 4;
    const int ccol = bn + wc * 64 + fr;
#pragma unroll
    for (int m = 0; m < 8; ++m)
#pragma unroll
        for (int n = 0; n < 4; ++n)
#pragma unroll
            for (int j = 0; j < 4; ++j)
                C[(size_t)(crow + m * 16 + j) * N_DIM + ccol + n * 16] = acc[m][n][j];
}

// ---------------------------------------------------------------------------
// fp32 fallback (only if ws too small)
// ---------------------------------------------------------------------------
__global__ void gemm_f32_fallback(const float* __restrict__ A,
                                  const float* __restrict__ B,
                                  float* __restrict__ C,
                                  const float* __restrict__ thrp) {
    __shared__ float As[32][33];
    __shared__ float Bs[32][33];
    const float thr = thrp[0];
    const int tx = threadIdx.x, ty = threadIdx.y;
    const int row = blockIdx.y * 32 + ty;
    float acc = 0.0f;
    for (int k0 = 0; k0 < K_DIM; k0 += 32) {
        float a = A[(size_t)row * K_DIM + k0 + tx];
        As[ty][tx] = (fabsf(a) > thr) ? a : 0.0f;
        Bs[ty][tx] = B[(size_t)(blockIdx.x * 32 + ty) * K_DIM + k0 + tx];
        __syncthreads();
#pragma unroll 8
        for (int kk = 0; kk < 32; ++kk)
            acc += As[ty][kk] * Bs[tx][kk];
        __syncthreads();
    }
    C[(size_t)row * N_DIM + blockIdx.x * 32 + tx] = acc;
}

// ---------------------------------------------------------------------------
extern "C" void kernel_launch(void* const* d_in, const int* in_sizes, int n_in,
                              void* d_out, int out_size, void* d_ws, size_t ws_size,
                              hipStream_t stream) {
    const float* x    = (const float*)d_in[0];
    const float* w    = (const float*)d_in[1];
    const float* thrp = (const float*)d_in[2];
    float* out = (float*)d_out;

    const size_t elems = (size_t)M_DIM * K_DIM;
    if (ws_size >= 2 * elems * sizeof(unsigned short)) {
        unsigned short* Ab = (unsigned short*)d_ws;
        unsigned short* Bb = Ab + elems;
        const int n8 = (int)(elems / 8);
        prune_cvt2<<<2048, 256, 0, stream>>>(x, w, Ab, Bb, thrp, n8);
        gemm_bgl<<<dim3(256), dim3(512), 0, stream>>>(Ab, Bb, out);
    } else {
        dim3 grid(N_DIM / 32, M_DIM / 32), blk(32, 32);
        gemm_f32_fallback<<<grid, blk, 0, stream>>>(x, w, out, thrp);
    }
}

// Round 15
// 142.624 us; speedup vs baseline: 1.5127x; 1.5127x over previous
//
#include <hip/hip_runtime.h>
#include <hip/hip_bf16.h>

#define M_DIM 4096
#define N_DIM 4096
#define K_DIM 4096

typedef __attribute__((ext_vector_type(8))) __bf16 bf16x8;
typedef __attribute__((ext_vector_type(8))) short short8;
typedef __attribute__((ext_vector_type(8))) unsigned short ushort8;
typedef __attribute__((ext_vector_type(4))) float f32x4;

// async global->LDS, 16B/lane (m104: dest = wave-uniform base + lane*16)
__device__ __forceinline__ void gload_lds16(const void* g, void* l) {
    __builtin_amdgcn_global_load_lds(
        (const __attribute__((address_space(1))) void*)g,
        (__attribute__((address_space(3))) void*)l,
        16, 0, 0);
}

__device__ __forceinline__ bf16x8 ld8(const unsigned short* p) {
    short8 r = *reinterpret_cast<const short8*>(p);
    return __builtin_bit_cast(bf16x8, r);
}

// ---------------------------------------------------------------------------
// fused fp32->bf16 conversion: x (pruned) and w (unpruned) in ONE launch
// ---------------------------------------------------------------------------
__global__ void prune_cvt2(const float* __restrict__ x,
                           const float* __restrict__ w,
                           unsigned short* __restrict__ xb,
                           unsigned short* __restrict__ wb,
                           const float* __restrict__ thrp, int n8) {
    const float thr = thrp[0];
    const int stride = gridDim.x * blockDim.x;
    const int total = 2 * n8;
    for (int idx = blockIdx.x * blockDim.x + threadIdx.x; idx < total; idx += stride) {
        const bool isx = idx < n8;
        const int j = isx ? idx : idx - n8;
        const float* src = isx ? x : w;
        unsigned short* dst = isx ? xb : wb;
        const float te = isx ? thr : -1.0f;   // |v| > -1 always true -> keep all
        const float4* p = reinterpret_cast<const float4*>(src) + 2 * (size_t)j;
        float4 v0 = p[0];
        float4 v1 = p[1];
        float v[8] = {v0.x, v0.y, v0.z, v0.w, v1.x, v1.y, v1.z, v1.w};
        ushort8 o;
#pragma unroll
        for (int e = 0; e < 8; ++e) {
            float f = v[e];
            f = (fabsf(f) > te) ? f : 0.0f;   // prune in fp32 (exact predicate)
            __hip_bfloat16 hh = __float2bfloat16(f);
            o[e] = *reinterpret_cast<unsigned short*>(&hh);
        }
        *reinterpret_cast<ushort8*>(dst + 8 * (size_t)j) = o;
    }
}

// ---------------------------------------------------------------------------
// C = A * B^T, 256x256 tile, BK=64, 8 waves, 16x16x32 MFMA, R6 skeleton with
// ONE barrier per K-tile (end-ph2): all 8 stages issue at ph0, the single
// lgkmcnt(0)+vmcnt(0)+s_barrier at end-ph2 lands them (~2 phases of slack,
// >HBM latency), and waves drift freely across ph3->ph0->ph1->ph2 so LDS
// read-storms of drifted waves overlap other waves' MFMA clusters.
//
// Hazard audit (1 barrier suffices):
//  RAW: tile t's LDS content staged @ph0(t-1), drained+published @end-ph2(t-1)
//       barrier; first read @ph3(t-1) (p-set from nxt) — after that barrier. OK
//  WAR: stage-writes @ph0(t) target buf nxt(t)=cur(t-1); last reads of that
//       content are @ph2(t-1) (s-frags), drained by lgkmcnt(0) before the
//       end-ph2(t-1) barrier; writes are after it. OK
//  B-frags are read same-phase @ph0 (champion-R6 behavior, proven).
//
// LDS per buffer: A[256][64], B[256][64], slot-swizzled:
//   element(row, logical col c) at row*64 + 8*((c>>3) ^ (row&7)) + (c&7)
// ---------------------------------------------------------------------------
__global__ __launch_bounds__(512, 2) void gemm_8phase(
        const unsigned short* __restrict__ A,
        const unsigned short* __restrict__ B,
        float* __restrict__ C) {
    __shared__ __align__(16) unsigned short lds[65536];  // 128 KB

    const int tid  = threadIdx.x;
    const int lane = tid & 63;
    const int wid  = tid >> 6;
    const int wr   = wid >> 2;   // 0..1 : 128-row strip
    const int wc   = wid & 3;    // 0..3 : 64-col strip

    // XCD-aware bijective swizzle (256 blocks / 8 XCDs)
    const int bid = blockIdx.x;
    const int swz = (bid & 7) * 32 + (bid >> 3);
    const int bm = (swz >> 4) * 256;
    const int bn = (swz & 15) * 256;

    // staging: A-half ah staged by threads [ah*256, +256); load j = rows [32j,+32)
    const int g  = tid & 255;
    const int ah = tid >> 8;
    const int arow = bm + ah * 128 + (g >> 3);
    const int acol = 8 * ((g & 7) ^ ((g >> 3) & 7));      // pre-swizzled source col
    const unsigned short* Asrc = A + (size_t)arow * K_DIM + acol;
    const int AdstE = ah * 8192 + g * 8;

    const int h = lane + 64 * wr;
    const int brow = bn + wc * 64 + (h >> 3);
    const int bcol = 8 * ((h & 7) ^ ((h >> 3) & 7));
    const unsigned short* Bsrc = B + (size_t)brow * K_DIM + bcol;
    const int BdstE = wc * 4096 + h * 8;

#define SA(dstb, j, kg) gload_lds16(Asrc + (size_t)(32*(j))*K_DIM + (kg), (dstb) + AdstE + 2048*(j))
#define SB(dstb, j, kg) gload_lds16(Bsrc + (size_t)(16*(j))*K_DIM + (kg), (dstb) + BdstE + 1024*(j))

    // fragment read offsets (row&7 == fr&7 -> swizzle slot is thread-constant)
    const int fr  = lane & 15;
    const int kq4 = lane >> 4;
    const int rowOffA = (wr * 128 + fr) * 64;
    const int rowOffB = (wc * 64 + fr) * 64;
    const int sk0 = 8 * ((kq4    ) ^ (fr & 7));
    const int sk1 = 8 * ((kq4 + 4) ^ (fr & 7));

    f32x4 acc[8][4] = {};

    bf16x8 bfr[4][2];
#define MFMA16(q, A00, A10, A01, A11)                                                              \
    __builtin_amdgcn_s_setprio(1);                                                                 \
    _Pragma("unroll")                                                                              \
    for (int n = 0; n < 4; ++n) {                                                                  \
        acc[2*(q)][n]   = __builtin_amdgcn_mfma_f32_16x16x32_bf16(A00, bfr[n][0], acc[2*(q)][n], 0, 0, 0);   \
        acc[2*(q)+1][n] = __builtin_amdgcn_mfma_f32_16x16x32_bf16(A10, bfr[n][0], acc[2*(q)+1][n], 0, 0, 0); \
    }                                                                                              \
    _Pragma("unroll")                                                                              \
    for (int n = 0; n < 4; ++n) {                                                                  \
        acc[2*(q)][n]   = __builtin_amdgcn_mfma_f32_16x16x32_bf16(A01, bfr[n][1], acc[2*(q)][n], 0, 0, 0);   \
        acc[2*(q)+1][n] = __builtin_amdgcn_mfma_f32_16x16x32_bf16(A11, bfr[n][1], acc[2*(q)+1][n], 0, 0, 0); \
    }                                                                                              \
    __builtin_amdgcn_s_setprio(0);

    // One K-tile body: reads (Ab,Bb); ALL stages for tile t+1 at ph0; ONE
    // lgkmcnt(0)+vmcnt(0)+barrier at end-ph2; ph3 pre-reads A(t+1)-j0.
#define TILE_BODY(Ab, Bb, AbN, BbN, kn)                                                            \
    {                                                                                              \
        /* ph0: MFMA j0 (p-set); read B(t)x8 + A(t)-j1; stage ALL 8 for t+1 */                     \
        _Pragma("unroll")                                                                          \
        for (int n = 0; n < 4; ++n) {                                                              \
            bfr[n][0] = ld8((Bb) + rowOffB + n * 1024 + sk0);                                      \
            bfr[n][1] = ld8((Bb) + rowOffB + n * 1024 + sk1);                                      \
        }                                                                                          \
        bf16x8 q00 = ld8((Ab) + rowOffA + 2 * 1024 + sk0);                                         \
        bf16x8 q10 = ld8((Ab) + rowOffA + 3 * 1024 + sk0);                                         \
        bf16x8 q01 = ld8((Ab) + rowOffA + 2 * 1024 + sk1);                                         \
        bf16x8 q11 = ld8((Ab) + rowOffA + 3 * 1024 + sk1);                                         \
        SB((BbN), 0, (kn)); SB((BbN), 1, (kn)); SB((BbN), 2, (kn)); SB((BbN), 3, (kn));            \
        SA((AbN), 0, (kn)); SA((AbN), 1, (kn)); SA((AbN), 2, (kn)); SA((AbN), 3, (kn));            \
        MFMA16(0, p00, p10, p01, p11);                                                             \
        /* ph1: MFMA j1 (q-set); read A(t)-j2 */                                                   \
        bf16x8 r00 = ld8((Ab) + rowOffA + 4 * 1024 + sk0);                                         \
        bf16x8 r10 = ld8((Ab) + rowOffA + 5 * 1024 + sk0);                                         \
        bf16x8 r01 = ld8((Ab) + rowOffA + 4 * 1024 + sk1);                                         \
        bf16x8 r11 = ld8((Ab) + rowOffA + 5 * 1024 + sk1);                                         \
        MFMA16(1, q00, q10, q01, q11);                                                             \
        /* ph2: MFMA j2 (r-set); read A(t)-j3; SINGLE sync point */                                \
        bf16x8 s00 = ld8((Ab) + rowOffA + 6 * 1024 + sk0);                                         \
        bf16x8 s10 = ld8((Ab) + rowOffA + 7 * 1024 + sk0);                                         \
        bf16x8 s01 = ld8((Ab) + rowOffA + 6 * 1024 + sk1);                                         \
        bf16x8 s11 = ld8((Ab) + rowOffA + 7 * 1024 + sk1);                                         \
        MFMA16(2, r00, r10, r01, r11);                                                             \
        asm volatile("s_waitcnt lgkmcnt(0) vmcnt(0)" ::: "memory");                                \
        asm volatile("s_barrier" ::: "memory");                                                    \
        /* ph3: MFMA j3 (s-set); pre-read A(t+1)-j0 from next buf */                               \
        p00 = ld8((AbN) + rowOffA + 0 * 1024 + sk0);                                               \
        p10 = ld8((AbN) + rowOffA + 1 * 1024 + sk0);                                               \
        p01 = ld8((AbN) + rowOffA + 0 * 1024 + sk1);                                               \
        p11 = ld8((AbN) + rowOffA + 1 * 1024 + sk1);                                               \
        MFMA16(3, s00, s10, s01, s11);                                                             \
    }

    // compile-time buffer bases
    unsigned short* A0 = lds;
    unsigned short* A1 = lds + 16384;
    unsigned short* B0 = lds + 32768;
    unsigned short* B1 = lds + 49152;

    // ---- prologue: stage tile0 into buf0; land everything; pre-read j0 frags
    SB(B0, 0, 0); SB(B0, 1, 0); SB(B0, 2, 0); SB(B0, 3, 0);
    SA(A0, 0, 0); SA(A0, 1, 0); SA(A0, 2, 0); SA(A0, 3, 0);
    asm volatile("s_waitcnt vmcnt(0)" ::: "memory");
    asm volatile("s_barrier" ::: "memory");

    bf16x8 p00 = ld8(A0 + rowOffA + 0 * 1024 + sk0);
    bf16x8 p10 = ld8(A0 + rowOffA + 1 * 1024 + sk0);
    bf16x8 p01 = ld8(A0 + rowOffA + 0 * 1024 + sk1);
    bf16x8 p11 = ld8(A0 + rowOffA + 1 * 1024 + sk1);

    for (int t = 0; t < 64; t += 2) {
        const int kn0 = (t + 1) * 64;                     // t+1 <= 63, never clamps
        const int kn1 = (t + 2 < 64 ? t + 2 : 63) * 64;   // clamp: tail stage is dead
        TILE_BODY(A0, B0, A1, B1, kn0);   // even tile: read buf0, stage buf1
        TILE_BODY(A1, B1, A0, B0, kn1);   // odd tile:  read buf1, stage buf0
    }

    asm volatile("s_waitcnt vmcnt(0)" ::: "memory");  // drain dead tail stages

    // C/D layout (m89): col = lane&15, row = (lane>>4)*4 + j
    const int crow = bm + wr * 128 + kq4 * 4;
    const int ccol = bn + wc * 64 + fr;
#pragma unroll
    for (int m = 0; m < 8; ++m)
#pragma unroll
        for (int n = 0; n < 4; ++n)
#pragma unroll
            for (int j = 0; j < 4; ++j)
                C[(size_t)(crow + m * 16 + j) * N_DIM + ccol + n * 16] = acc[m][n][j];
}

// ---------------------------------------------------------------------------
// fp32 fallback (only if ws too small)
// ---------------------------------------------------------------------------
__global__ void gemm_f32_fallback(const float* __restrict__ A,
                                  const float* __restrict__ B,
                                  float* __restrict__ C,
                                  const float* __restrict__ thrp) {
    __shared__ float As[32][33];
    __shared__ float Bs[32][33];
    const float thr = thrp[0];
    const int tx = threadIdx.x, ty = threadIdx.y;
    const int row = blockIdx.y * 32 + ty;
    float acc = 0.0f;
    for (int k0 = 0; k0 < K_DIM; k0 += 32) {
        float a = A[(size_t)row * K_DIM + k0 + tx];
        As[ty][tx] = (fabsf(a) > thr) ? a : 0.0f;
        Bs[ty][tx] = B[(size_t)(blockIdx.x * 32 + ty) * K_DIM + k0 + tx];
        __syncthreads();
#pragma unroll 8
        for (int kk = 0; kk < 32; ++kk)
            acc += As[ty][kk] * Bs[tx][kk];
        __syncthreads();
    }
    C[(size_t)row * N_DIM + blockIdx.x * 32 + tx] = acc;
}

// ---------------------------------------------------------------------------
extern "C" void kernel_launch(void* const* d_in, const int* in_sizes, int n_in,
                              void* d_out, int out_size, void* d_ws, size_t ws_size,
                              hipStream_t stream) {
    const float* x    = (const float*)d_in[0];
    const float* w    = (const float*)d_in[1];
    const float* thrp = (const float*)d_in[2];
    float* out = (float*)d_out;

    const size_t elems = (size_t)M_DIM * K_DIM;
    if (ws_size >= 2 * elems * sizeof(unsigned short)) {
        unsigned short* Ab = (unsigned short*)d_ws;
        unsigned short* Bb = Ab + elems;
        const int n8 = (int)(elems / 8);
        prune_cvt2<<<2048, 256, 0, stream>>>(x, w, Ab, Bb, thrp, n8);
        gemm_8phase<<<dim3(256), dim3(512), 0, stream>>>(Ab, Bb, out);
    } else {
        dim3 grid(N_DIM / 32, M_DIM / 32), blk(32, 32);
        gemm_f32_fallback<<<grid, blk, 0, stream>>>(x, w, out, thrp);
    }
}